// Round 6
// baseline (213.023 us; speedup 1.0000x reference)
//
#include <hip/hip_runtime.h>

#define B_   8
#define D_   256
#define HW_  16384
#define NC_  48     // NCLS*K
#define KO_  128    // key channels
#define PT_  32     // pixels per tile

using bf16x8 = __attribute__((ext_vector_type(8))) short;
using f32x4  = __attribute__((ext_vector_type(4))) float;
typedef unsigned long long ull;

__device__ __forceinline__ unsigned short f2bf(float f) {
  unsigned int u = __float_as_uint(f);
  u += 0x7FFFu + ((u >> 16) & 1u);   // RNE
  return (unsigned short)(u >> 16);
}
__device__ __forceinline__ ull pack4bf(float a, float b, float c, float d) {
  return (ull)f2bf(a) | ((ull)f2bf(b) << 16)
       | ((ull)f2bf(c) << 32) | ((ull)f2bf(d) << 48);
}

// ---------------- P1: q = Wq.protos + bq ; M = q.Wk packed to MFMA frag order ;
//                      beta = q.bk ; nrmb = ||proto||^2 ; pixlist ----------------
__global__ __launch_bounds__(256) void p1_kernel(
    const float* __restrict__ protos, const float* __restrict__ Wq,
    const float* __restrict__ bq, const float* __restrict__ Wk,
    const float* __restrict__ bk, const int* __restrict__ xc,
    const int* __restrict__ yc,
    unsigned short* __restrict__ m_pk, float* __restrict__ beta,
    float* __restrict__ nrmb, int* __restrict__ pixlist,
    float* __restrict__ protos_out, int pcnt) {
  __shared__ float qs[KO_];
  __shared__ float sc2[2][KO_][2];
  const int c = blockIdx.x;   // 0..47
  const int b = blockIdx.y;   // 0..7
  const int t = threadIdx.x;  // 0..255
  const int o = t & 127, h = t >> 7;
  const int i = c >> 3;
  const float* pp = protos + ((size_t)b * NC_ + c) * D_;
  // phase A: q = Wq.proto + bq (K-split over h)
  {
    const float* wq = Wq + ((size_t)i * KO_ + o) * D_ + h * 128;
    const float* ph = pp + h * 128;
    float acc = 0.f;
    for (int d = 0; d < 128; d += 4) {
      float4 wv = *(const float4*)(wq + d);
      float4 pv = *(const float4*)(ph + d);
      acc += wv.x * pv.x + wv.y * pv.y + wv.z * pv.z + wv.w * pv.w;
    }
    sc2[h][o][0] = acc;
  }
  __syncthreads();
  if (h == 0) {
    float q = sc2[0][o][0] + sc2[1][o][0] + bq[i * KO_ + o];
    qs[o] = q;
    protos_out[((size_t)c * B_ + b) * KO_ + o] = q;
  }
  __syncthreads();
  // phase B: M[c][2o..2o+1] = sum_oo q[oo]*Wk[oo][2o..], K-split over h
  {
    float m0 = 0.f, m1 = 0.f;
    for (int oo = h * 64; oo < h * 64 + 64; ++oo) {
      float2 wv = *(const float2*)(Wk + (size_t)oo * D_ + o * 2);
      float qv = qs[oo];
      m0 += qv * wv.x; m1 += qv * wv.y;
    }
    sc2[h][o][0] = m0; sc2[h][o][1] = m1;
  }
  __syncthreads();
  if (h == 0) {
    float M0 = sc2[0][o][0] + sc2[1][o][0];
    float M1 = sc2[0][o][1] + sc2[1][o][1];
    // repack: d=2o -> ks=o>>4, g=(o>>2)&3, ii=(o&3)*2 ; ct=c>>4, lr=c&15
    const int ks = o >> 4, gg = (o >> 2) & 3, ii = (o & 3) * 2;
    const int ct = c >> 4, lrr = c & 15;
    const size_t fidx = ((size_t)(b * 24 + ks * 3 + ct) * 64 + gg * 16 + lrr) * 8 + ii;
    *(unsigned*)(m_pk + fidx) = (unsigned)f2bf(M0) | ((unsigned)f2bf(M1) << 16);
  }
  // phase C/D: beta = q.bk ; nrmb = ||proto||^2 (wave 0)
  if (t < 64) {
    float p = qs[t] * bk[t] + qs[t + 64] * bk[t + 64];
    float4 pv = *(const float4*)(pp + t * 4);
    float nn = pv.x * pv.x + pv.y * pv.y + pv.z * pv.z + pv.w * pv.w;
    for (int off = 32; off; off >>= 1) {
      p  += __shfl_down(p, off);
      nn += __shfl_down(nn, off);
    }
    if (t == 0) { beta[b * NC_ + c] = p; nrmb[b * NC_ + c] = nn; }
  }
  // phase E: pixlist
  const int gid = (b * NC_ + c) * 256 + t;
  if (gid < pcnt) pixlist[gid] = xc[gid] * 128 + yc[gid];
}

#define EXTRACT_J(J)                                        \
  _Pragma("unroll")                                         \
  for (int it = 0; it < 4; ++it) {                          \
    vsel[it * 4 + 0] = V[it * 16 + 0 * 4 + (J)];            \
    vsel[it * 4 + 1] = V[it * 16 + 1 * 4 + (J)];            \
    vsel[it * 4 + 2] = V[it * 16 + 2 * 4 + (J)];            \
    vsel[it * 4 + 3] = V[it * 16 + 3 * 4 + (J)];            \
  }

#define SUBST_J(J)                                          \
  _Pragma("unroll")                                         \
  for (int it = 0; it < 4; ++it) {                          \
    float4 pv = *(const float4*)(prc + it * 64);            \
    V[it * 16 + 0 * 4 + (J)] = pv.x;                        \
    V[it * 16 + 1 * 4 + (J)] = pv.y;                        \
    V[it * 16 + 2 * 4 + (J)] = pv.z;                        \
    V[it * 16 + 3 * 4 + (J)] = pv.w;                        \
  }

// ---------------- M: fused argmin + replace + sim GEMM + softmax + outputs ----------------
// 128 threads (2 waves), 32 pixels/block, fully wave-independent (no __syncthreads).
// Wave w owns pixels [w*16, w*16+16). Lane l: pixel quad pq=l&3, d-quad dr=l>>2.
// LDS F tile: bf16 [p][d], 512B rows, byte swizzle X(p) = ((p&7)<<4) ^ ((p>>3)<<3).
__global__ __launch_bounds__(128, 3) void m_kernel(
    const float* __restrict__ feats, const float* __restrict__ protos,
    const unsigned short* __restrict__ m_pk, const float* __restrict__ beta,
    const float* __restrict__ nrmb, const int* __restrict__ pixlist, int pcnt,
    float* __restrict__ out_assp, float* __restrict__ out_wmax,
    float* __restrict__ out_sim, float* __restrict__ out_wmean) {
  __shared__ __align__(16) unsigned short Fb[PT_ * 256];   // 16 KB

  const int tid  = threadIdx.x;   // 0..127
  const int lane = tid & 63;
  const int wid  = tid >> 6;      // 0..1
  const int pq   = lane & 3;      // pixel quad within wave's 16
  const int dr   = lane >> 2;     // 0..15 d-quad
  const int g    = lane >> 4;     // 0..3 (GEMM)
  const int lr   = lane & 15;     // (GEMM)
  const int b    = blockIdx.y;
  const int p0   = blockIdx.x * PT_;
  unsigned char* fbB = (unsigned char*)Fb;

  // ---- 1. load raw F columns into registers ----
  float V[64];   // V[it*16 + k*4 + j] = F[it*64+dr*4+k][wid*16+pq*4+j]
  const float* fb = feats + (size_t)b * D_ * HW_ + p0 + wid * 16 + pq * 4;
  #pragma unroll
  for (int it = 0; it < 4; ++it)
    #pragma unroll
    for (int k = 0; k < 4; ++k) {
      float4 t = *(const float4*)(fb + (size_t)(it * 64 + dr * 4 + k) * HW_);
      V[it*16 + k*4 + 0] = t.x; V[it*16 + k*4 + 1] = t.y;
      V[it*16 + k*4 + 2] = t.z; V[it*16 + k*4 + 3] = t.w;
    }

  // ---- 2. find sampled pixels in this wave's 16 (scan pixlist) ----
  unsigned lm = 0;
  {
    const int wbase = p0 + wid * 16;
    for (int i2 = lane; i2 < pcnt; i2 += 64) {
      int dp = pixlist[i2] - wbase;
      if ((unsigned)dp < 16u) lm |= 1u << dp;
    }
    #pragma unroll
    for (int s = 1; s < 64; s <<= 1) lm |= (unsigned)__shfl_xor((int)lm, s);
  }

  // ---- 3. per sampled pixel: exact f32 argmin over 48 protos, substitute ----
  const float* prb = protos + (size_t)b * NC_ * D_ + dr * 4;
  while (lm) {
    const int pp = __ffs(lm) - 1; lm &= lm - 1;   // wave-uniform
    const int tq = pp >> 2, j = pp & 3;
    float vsel[16];
    switch (j) {
      case 0: EXTRACT_J(0) break;
      case 1: EXTRACT_J(1) break;
      case 2: EXTRACT_J(2) break;
      default: EXTRACT_J(3) break;
    }
    float best = 3.4e38f; int cb = 0;
    for (int c = 0; c < NC_; ++c) {
      const float* prc = prb + (size_t)c * D_;
      float dot = 0.f;
      #pragma unroll
      for (int it = 0; it < 4; ++it) {
        float4 pv = *(const float4*)(prc + it * 64);
        dot += pv.x * vsel[it*4+0] + pv.y * vsel[it*4+1]
             + pv.z * vsel[it*4+2] + pv.w * vsel[it*4+3];
      }
      dot += __shfl_xor(dot, 4);  dot += __shfl_xor(dot, 8);
      dot += __shfl_xor(dot, 16); dot += __shfl_xor(dot, 32);
      float d2v = nrmb[b * NC_ + c] - 2.f * dot;
      if (d2v < best) { best = d2v; cb = c; }   // '<' keeps first index on ties
    }
    if (pq == tq) {
      const float* prc = prb + (size_t)cb * D_;
      switch (j) {
        case 0: SUBST_J(0) break;
        case 1: SUBST_J(1) break;
        case 2: SUBST_J(2) break;
        default: SUBST_J(3) break;
      }
    }
  }

  // ---- 4. write F tile to LDS (bf16, swizzled; wave-local rows) ----
  #pragma unroll
  for (int it = 0; it < 4; ++it)
    #pragma unroll
    for (int j = 0; j < 4; ++j) {
      const int p = wid * 16 + pq * 4 + j;
      const unsigned X = (unsigned)(((p & 7) << 4) ^ ((p >> 3) << 3));
      *(ull*)(fbB + p * 512 + ((unsigned)(it * 128 + dr * 8) ^ X)) =
          pack4bf(V[it*16 + 0*4 + j], V[it*16 + 1*4 + j],
                  V[it*16 + 2*4 + j], V[it*16 + 3*4 + j]);
    }
  asm volatile("s_waitcnt lgkmcnt(0)" ::: "memory");

  // ---- 5. sim GEMM: sim[c][p] = M(48x256) x F(256x32) + beta ----
  const int p = wid * 16 + lr;
  const unsigned Xp = (unsigned)(((p & 7) << 4) ^ ((p >> 3) << 3));
  f32x4 sacc[3] = {};
  {
    const unsigned short* apk = m_pk + (size_t)b * 24 * 64 * 8 + lane * 8;
    #pragma unroll
    for (int ks = 0; ks < 8; ++ks) {
      const unsigned base = (unsigned)(ks * 64 + g * 16);
      ull lo = *(const ull*)(fbB + p * 512 + (base ^ Xp));
      ull hi = *(const ull*)(fbB + p * 512 + ((base + 8) ^ Xp));
      union { ull u[2]; bf16x8 v8; } bu;
      bu.u[0] = lo; bu.u[1] = hi;
      #pragma unroll
      for (int ct = 0; ct < 3; ++ct) {
        bf16x8 af = *(const bf16x8*)(apk + (size_t)(ks * 3 + ct) * 64 * 8);
        sacc[ct] = __builtin_amdgcn_mfma_f32_16x16x32_bf16(af, bu.v8, sacc[ct], 0, 0, 0);
      }
    }
  }

  // ---- 6. + beta, softmax over c (lanes xor 16/32 share a pixel) ----
  #pragma unroll
  for (int ct = 0; ct < 3; ++ct) {
    float4 bt = *(const float4*)(beta + b * NC_ + ct * 16 + g * 4);
    sacc[ct][0] += bt.x; sacc[ct][1] += bt.y;
    sacc[ct][2] += bt.z; sacc[ct][3] += bt.w;
  }
  float m = -3.4e38f;
  #pragma unroll
  for (int ct = 0; ct < 3; ++ct)
    #pragma unroll
    for (int r = 0; r < 4; ++r) m = fmaxf(m, sacc[ct][r]);
  m = fmaxf(m, __shfl_xor(m, 16));
  m = fmaxf(m, __shfl_xor(m, 32));
  const float sc = 1.0f / 6.0f;   // K/C = 8/48
  float s = 0.f;
  #pragma unroll
  for (int ct = 0; ct < 3; ++ct)
    #pragma unroll
    for (int r = 0; r < 4; ++r) s += __expf((sacc[ct][r] - m) * sc);
  s += __shfl_xor(s, 16);
  s += __shfl_xor(s, 32);
  const float wmax = 1.f / s;

  // ---- 7. sim / wmax / wmean stores (each instr covers full 64B lines) ----
  const size_t pixg = (size_t)p0 + p;
  #pragma unroll
  for (int ct = 0; ct < 3; ++ct)
    #pragma unroll
    for (int r = 0; r < 4; ++r)
      out_sim[((size_t)b * NC_ + ct * 16 + g * 4 + r) * HW_ + pixg] = sacc[ct][r];
  if (g == 0) {
    out_wmax[(size_t)b * HW_ + pixg] = wmax;
    out_wmean[(size_t)b * HW_ + pixg] = 1.f / 48.f;
  }

  // ---- 8. weighted output from registers (f32 exact) ----
  {
    const float w0 = __shfl(wmax, wid * 64 ? 0 : 0 + pq * 4 + 0);  // lanes 0..15 hold pixels
    const float w1 = __shfl(wmax, pq * 4 + 1);
    const float w2 = __shfl(wmax, pq * 4 + 2);
    const float w3 = __shfl(wmax, pq * 4 + 3);
    const float ww0 = __shfl(wmax, pq * 4 + 0);
    float* oa = out_assp + (size_t)b * D_ * HW_ + p0 + wid * 16 + pq * 4;
    #pragma unroll
    for (int it = 0; it < 4; ++it)
      #pragma unroll
      for (int k = 0; k < 4; ++k) {
        float4 o;
        o.x = V[it*16 + k*4 + 0] * ww0;
        o.y = V[it*16 + k*4 + 1] * w1;
        o.z = V[it*16 + k*4 + 2] * w2;
        o.w = V[it*16 + k*4 + 3] * w3;
        *(float4*)(oa + (size_t)(it * 64 + dr * 4 + k) * HW_) = o;
      }
  }
}

extern "C" void kernel_launch(void* const* d_in, const int* in_sizes, int n_in,
                              void* d_out, int out_size, void* d_ws, size_t ws_size,
                              hipStream_t stream) {
  const float* feats  = (const float*)d_in[0];
  const float* protos = (const float*)d_in[1];
  const float* Wk     = (const float*)d_in[2];
  const float* bk     = (const float*)d_in[3];
  const float* Wq     = (const float*)d_in[4];
  const float* bq     = (const float*)d_in[5];
  const int*   xc     = (const int*)d_in[6];
  const int*   yc     = (const int*)d_in[7];
  const int    P      = in_sizes[6];   // 819

  float* out       = (float*)d_out;
  float* out_assp  = out;                                  // B*D*HW
  float* out_po    = out_assp + (size_t)B_ * D_ * HW_;     // 48*B*128
  float* out_wmax  = out_po + (size_t)NC_ * B_ * KO_;      // B*HW
  float* out_sim   = out_wmax + (size_t)B_ * HW_;          // B*48*HW
  float* out_wmean = out_sim + (size_t)B_ * NC_ * HW_;     // B*HW

  unsigned char* ws = (unsigned char*)d_ws;
  unsigned short* m_pk = (unsigned short*)ws;                    // 196608 B
  float* beta          = (float*)(ws + 196608);                  // 1536 B
  float* nrmb          = (float*)(ws + 198144);                  // 1536 B
  int* pixlist         = (int*)(ws + 199680);                    // 4096 B

  p1_kernel<<<dim3(NC_, B_), 256, 0, stream>>>(protos, Wq, bq, Wk, bk, xc, yc,
                                               m_pk, beta, nrmb, pixlist, out_po, P);
  m_kernel<<<dim3(HW_ / PT_, B_), 128, 0, stream>>>(feats, protos, m_pk, beta, nrmb,
                                                    pixlist, P,
                                                    out_assp, out_wmax, out_sim, out_wmean);
}

// Round 7
// 143.197 us; speedup vs baseline: 1.4876x; 1.4876x over previous
//
#include <hip/hip_runtime.h>

#define B_   8
#define D_   256
#define HW_  16384
#define NC_  48     // NCLS*K
#define KO_  128    // key channels
#define PT_  32     // pixels per tile
#define TT_  4      // tiles per block

using bf16x8 = __attribute__((ext_vector_type(8))) short;
using f32x4  = __attribute__((ext_vector_type(4))) float;
typedef unsigned long long ull;

__device__ __forceinline__ unsigned short f2bf(float f) {
  unsigned int u = __float_as_uint(f);
  u += 0x7FFFu + ((u >> 16) & 1u);   // RNE
  return (unsigned short)(u >> 16);
}
__device__ __forceinline__ ull pack4bf(float a, float b, float c, float d) {
  return (ull)f2bf(a) | ((ull)f2bf(b) << 16)
       | ((ull)f2bf(c) << 32) | ((ull)f2bf(d) << 48);
}

// ---------------- P1: q = Wq.protos + bq ; M = q.Wk packed to MFMA frag order ;
//                      beta = q.bk ; map init ----------------
__global__ __launch_bounds__(256) void p1_kernel(
    const float* __restrict__ protos, const float* __restrict__ Wq,
    const float* __restrict__ bq, const float* __restrict__ Wk,
    const float* __restrict__ bk,
    unsigned short* __restrict__ m_pk, float* __restrict__ beta,
    float* __restrict__ protos_out, int* __restrict__ map_i) {
  __shared__ float qs[KO_];
  __shared__ float sc2[2][KO_][2];
  const int c = blockIdx.x;   // 0..47
  const int b = blockIdx.y;   // 0..7
  const int t = threadIdx.x;  // 0..255
  const int o = t & 127, h = t >> 7;
  const int i = c >> 3;
  const float* pp = protos + ((size_t)b * NC_ + c) * D_;
  // phase A: q = Wq.proto + bq (K-split over h)
  {
    const float* wq = Wq + ((size_t)i * KO_ + o) * D_ + h * 128;
    const float* ph = pp + h * 128;
    float acc = 0.f;
    for (int d = 0; d < 128; d += 4) {
      float4 wv = *(const float4*)(wq + d);
      float4 pv = *(const float4*)(ph + d);
      acc += wv.x * pv.x + wv.y * pv.y + wv.z * pv.z + wv.w * pv.w;
    }
    sc2[h][o][0] = acc;
  }
  __syncthreads();
  if (h == 0) {
    float q = sc2[0][o][0] + sc2[1][o][0] + bq[i * KO_ + o];
    qs[o] = q;
    protos_out[((size_t)c * B_ + b) * KO_ + o] = q;
  }
  __syncthreads();
  // phase B: M[c][2o..2o+1] = sum_oo q[oo]*Wk[oo][2o..], K-split over h
  {
    float m0 = 0.f, m1 = 0.f;
    for (int oo = h * 64; oo < h * 64 + 64; ++oo) {
      float2 wv = *(const float2*)(Wk + (size_t)oo * D_ + o * 2);
      float qv = qs[oo];
      m0 += qv * wv.x; m1 += qv * wv.y;
    }
    sc2[h][o][0] = m0; sc2[h][o][1] = m1;
  }
  __syncthreads();
  if (h == 0) {
    float M0 = sc2[0][o][0] + sc2[1][o][0];
    float M1 = sc2[0][o][1] + sc2[1][o][1];
    // repack: d=2o -> ks=o>>4, g=(o>>2)&3, ii=(o&3)*2 ; ct=c>>4, lr=c&15
    const int ks = o >> 4, gg = (o >> 2) & 3, ii = (o & 3) * 2;
    const int ct = c >> 4, lrr = c & 15;
    const size_t fidx = ((size_t)(b * 24 + ks * 3 + ct) * 64 + gg * 16 + lrr) * 8 + ii;
    *(unsigned*)(m_pk + fidx) = (unsigned)f2bf(M0) | ((unsigned)f2bf(M1) << 16);
  }
  // phase C: beta = q.bk (wave 0)
  if (t < 64) {
    float p = qs[t] * bk[t] + qs[t + 64] * bk[t + 64];
    for (int off = 32; off; off >>= 1) p += __shfl_down(p, off);
    if (t == 0) beta[b * NC_ + c] = p;
  }
  // phase D: map init (-1 everywhere)
  const int gid = (b * NC_ + c) * 256 + t;
  if (gid < B_ * HW_ / 4) map_i[gid] = -1;
}

// ---------------- P2: nearest prototype per sampled pixel -> map (exact f32) ----------------
__global__ void p2_kernel(const float* __restrict__ feats,
                          const float* __restrict__ protos,
                          const int* __restrict__ xc,
                          const int* __restrict__ yc,
                          signed char* __restrict__ map) {
  const int sp = blockIdx.x;
  const int b  = blockIdx.y;
  const int lane = threadIdx.x;  // 0..63
  __shared__ float sel[D_];
  const int pix = xc[sp] * 128 + yc[sp];
  const float* fb = feats + (size_t)b * D_ * HW_ + pix;
  for (int k = 0; k < 4; ++k) {
    int d = lane + k * 64;
    sel[d] = fb[(size_t)d * HW_];
  }
  __syncthreads();
  float d2 = 3.4e38f;
  int bi = lane;
  if (lane < NC_) {
    const float* pf = protos + ((size_t)b * NC_ + lane) * D_;
    float nrm = 0.f, dot = 0.f;
    for (int d = 0; d < D_; d += 4) {
      float4 pv = *(const float4*)(pf + d);
      float4 sv = *(const float4*)(sel + d);
      nrm += pv.x * pv.x + pv.y * pv.y + pv.z * pv.z + pv.w * pv.w;
      dot += pv.x * sv.x + pv.y * sv.y + pv.z * sv.z + pv.w * sv.w;
    }
    d2 = nrm - 2.f * dot;
  }
  for (int off = 32; off > 0; off >>= 1) {
    float ov = __shfl_down(d2, off);
    int   oi = __shfl_down(bi, off);
    if (ov < d2 || (ov == d2 && oi < bi)) { d2 = ov; bi = oi; }
  }
  if (lane == 0) map[(size_t)b * HW_ + pix] = (signed char)bi;
}

// ---------------- M: fused replace + sim GEMM + softmax + outputs ----------------
// R5-verified structure, 4 tiles/block. 128 threads (2 waves), 32 pixels/tile.
// A-fragments (24 x bf16x8) and beta held in registers across all 4 tiles.
// LDS F tile: bf16 [p][d], 512B rows, byte swizzle X(p) = ((p&7)<<4) ^ ((p>>3)<<3).
__global__ __launch_bounds__(128, 2) void m_kernel(
    const float* __restrict__ feats, const float* __restrict__ protos,
    const unsigned short* __restrict__ m_pk, const float* __restrict__ beta,
    const signed char* __restrict__ map,
    float* __restrict__ out_assp, float* __restrict__ out_wmax,
    float* __restrict__ out_sim, float* __restrict__ out_wmean) {
  __shared__ __align__(16) unsigned short Fb[PT_ * 256];   // 16 KB
  __shared__ __align__(16) float simb[NC_ * PT_];          // 6 KB
  __shared__ float wm[PT_];
  __shared__ signed char map_s[TT_ * PT_];

  const int tid  = threadIdx.x;   // 0..127
  const int lane = tid & 63;
  const int wid  = tid >> 6;      // 0..1
  const int g    = lane >> 4;     // 0..3
  const int lr   = lane & 15;
  const int b    = blockIdx.y;
  const int P0   = blockIdx.x * (TT_ * PT_);

  map_s[tid] = map[(size_t)b * HW_ + P0 + tid];   // 128 pixels = all 4 tiles

  // ---- A-fragments + beta: load once, reuse across tiles ----
  bf16x8 A[24];
  {
    const unsigned short* apk = m_pk + (size_t)b * 24 * 64 * 8 + lane * 8;
    #pragma unroll
    for (int f = 0; f < 24; ++f)
      A[f] = *(const bf16x8*)(apk + (size_t)f * 512);
  }
  float4 bt[3];
  #pragma unroll
  for (int ct = 0; ct < 3; ++ct)
    bt[ct] = *(const float4*)(beta + b * NC_ + ct * 16 + g * 4);

  unsigned char* fbB = (unsigned char*)Fb;
  const int x  = tid & 7;     // pixel quad: pixels x*4..x*4+3
  const int dr = tid >> 3;    // 0..15
  const int p  = wid * 16 + lr;
  const unsigned Xp = (unsigned)(((p & 7) << 4) ^ ((p >> 3) << 3));
  __syncthreads();   // map_s visible

  for (int t = 0; t < TT_; ++t) {
    const int p0 = P0 + t * PT_;

    // ---- stage: 16 dwordx4 loads, in-reg substitute+transpose, 16 ds_write_b64 ----
    float V[64];   // V[it*16 + k*4 + j] = F[it*64+dr*4+k][x*4+j]
    {
      const float* fb = feats + (size_t)b * D_ * HW_ + p0 + x * 4;
      const float* prb = protos + (size_t)b * NC_ * D_;
      int cj[4];
      #pragma unroll
      for (int j = 0; j < 4; ++j) cj[j] = map_s[t * PT_ + x * 4 + j];
      #pragma unroll
      for (int it = 0; it < 4; ++it) {
        const int d0 = it * 64 + dr * 4;
        #pragma unroll
        for (int k = 0; k < 4; ++k) {
          float4 tv = *(const float4*)(fb + (size_t)(d0 + k) * HW_);
          V[it*16 + k*4 + 0] = tv.x; V[it*16 + k*4 + 1] = tv.y;
          V[it*16 + k*4 + 2] = tv.z; V[it*16 + k*4 + 3] = tv.w;
        }
        #pragma unroll
        for (int j = 0; j < 4; ++j) {
          if (cj[j] >= 0) {
            float4 pv = *(const float4*)(prb + (size_t)cj[j] * D_ + d0);
            V[it*16 + 0*4 + j] = pv.x; V[it*16 + 1*4 + j] = pv.y;
            V[it*16 + 2*4 + j] = pv.z; V[it*16 + 3*4 + j] = pv.w;
          }
        }
        #pragma unroll
        for (int j = 0; j < 4; ++j) {
          const int pw = x * 4 + j;
          const unsigned X = (unsigned)(((pw & 7) << 4) ^ ((pw >> 3) << 3));
          *(ull*)(fbB + pw * 512 + ((unsigned)(d0 * 2) ^ X)) =
              pack4bf(V[it*16 + 0*4 + j], V[it*16 + 1*4 + j],
                      V[it*16 + 2*4 + j], V[it*16 + 3*4 + j]);
        }
      }
    }
    __syncthreads();

    // ---- sim GEMM: sim[c][p] = M(48x256) x F(256x32) + beta ----
    f32x4 sacc[3] = {};
    #pragma unroll
    for (int ks = 0; ks < 8; ++ks) {
      const unsigned base = (unsigned)(ks * 64 + g * 16);
      ull lo = *(const ull*)(fbB + p * 512 + (base ^ Xp));
      ull hi = *(const ull*)(fbB + p * 512 + ((base + 8) ^ Xp));
      union { ull u[2]; bf16x8 v8; } bu;
      bu.u[0] = lo; bu.u[1] = hi;
      #pragma unroll
      for (int ct = 0; ct < 3; ++ct)
        sacc[ct] = __builtin_amdgcn_mfma_f32_16x16x32_bf16(A[ks * 3 + ct], bu.v8,
                                                           sacc[ct], 0, 0, 0);
    }

    // ---- + beta, softmax over c (lanes xor 16/32 share a pixel) ----
    #pragma unroll
    for (int ct = 0; ct < 3; ++ct) {
      sacc[ct][0] += bt[ct].x; sacc[ct][1] += bt[ct].y;
      sacc[ct][2] += bt[ct].z; sacc[ct][3] += bt[ct].w;
    }
    float m = -3.4e38f;
    #pragma unroll
    for (int ct = 0; ct < 3; ++ct)
      #pragma unroll
      for (int r = 0; r < 4; ++r) m = fmaxf(m, sacc[ct][r]);
    m = fmaxf(m, __shfl_xor(m, 16));
    m = fmaxf(m, __shfl_xor(m, 32));
    const float sc = 1.0f / 6.0f;   // K/C = 8/48
    float s = 0.f;
    #pragma unroll
    for (int ct = 0; ct < 3; ++ct)
      #pragma unroll
      for (int r = 0; r < 4; ++r) s += __expf((sacc[ct][r] - m) * sc);
    s += __shfl_xor(s, 16);
    s += __shfl_xor(s, 32);
    const float wmax = 1.f / s;

    // ---- sacc -> simb ; wm ----
    #pragma unroll
    for (int ct = 0; ct < 3; ++ct)
      #pragma unroll
      for (int r = 0; r < 4; ++r)
        simb[(ct * 16 + g * 4 + r) * PT_ + p] = sacc[ct][r];
    const size_t pixg = (size_t)p0 + p;
    if (g == 0) {
      wm[p] = wmax;
      out_wmax[(size_t)b * HW_ + pixg] = wmax;
      out_wmean[(size_t)b * HW_ + pixg] = 1.f / 48.f;
    }
    __syncthreads();

    // ---- sim stores: float4 across pixels ----
    #pragma unroll
    for (int r3 = 0; r3 < 3; ++r3) {
      const int f  = r3 * 128 + tid;   // 0..383
      const int c  = f >> 3;
      const int po = (f & 7) * 4;
      float4 sv = *(const float4*)(simb + c * PT_ + po);
      *(float4*)(out_sim + ((size_t)b * NC_ + c) * HW_ + p0 + po) = sv;
    }

    // ---- weighted output from registers (f32 exact) ----
    {
      float4 w4 = *(const float4*)(wm + x * 4);
      float* oa = out_assp + (size_t)b * D_ * HW_ + p0 + x * 4;
      #pragma unroll
      for (int it = 0; it < 4; ++it) {
        const int d0 = it * 64 + dr * 4;
        #pragma unroll
        for (int k = 0; k < 4; ++k) {
          float4 o;
          o.x = V[it*16 + k*4 + 0] * w4.x;
          o.y = V[it*16 + k*4 + 1] * w4.y;
          o.z = V[it*16 + k*4 + 2] * w4.z;
          o.w = V[it*16 + k*4 + 3] * w4.w;
          *(float4*)(oa + (size_t)(d0 + k) * HW_) = o;
        }
      }
    }
    __syncthreads();   // simb/wm reads done; Fb free for next tile
  }
}

extern "C" void kernel_launch(void* const* d_in, const int* in_sizes, int n_in,
                              void* d_out, int out_size, void* d_ws, size_t ws_size,
                              hipStream_t stream) {
  const float* feats  = (const float*)d_in[0];
  const float* protos = (const float*)d_in[1];
  const float* Wk     = (const float*)d_in[2];
  const float* bk     = (const float*)d_in[3];
  const float* Wq     = (const float*)d_in[4];
  const float* bq     = (const float*)d_in[5];
  const int*   xc     = (const int*)d_in[6];
  const int*   yc     = (const int*)d_in[7];
  const int    P      = in_sizes[6];   // 819

  float* out       = (float*)d_out;
  float* out_assp  = out;                                  // B*D*HW
  float* out_po    = out_assp + (size_t)B_ * D_ * HW_;     // 48*B*128
  float* out_wmax  = out_po + (size_t)NC_ * B_ * KO_;      // B*HW
  float* out_sim   = out_wmax + (size_t)B_ * HW_;          // B*48*HW
  float* out_wmean = out_sim + (size_t)B_ * NC_ * HW_;     // B*HW

  unsigned char* ws = (unsigned char*)d_ws;
  unsigned short* m_pk = (unsigned short*)ws;                    // 196608 B
  float* beta          = (float*)(ws + 196608);                  // 1536 B
  signed char* map     = (signed char*)(ws + 198144);            // 131072 B

  p1_kernel<<<dim3(NC_, B_), 256, 0, stream>>>(protos, Wq, bq, Wk, bk,
                                               m_pk, beta, out_po, (int*)map);
  p2_kernel<<<dim3(P, B_), 64, 0, stream>>>(feats, protos, xc, yc, map);
  m_kernel<<<dim3(HW_ / (TT_ * PT_), B_), 128, 0, stream>>>(feats, protos, m_pk, beta, map,
                                                            out_assp, out_wmax, out_sim,
                                                            out_wmean);
}